// Round 2
// baseline (209.082 us; speedup 1.0000x reference)
//
#include <hip/hip_runtime.h>

// ---------- common helpers ----------
typedef __attribute__((ext_vector_type(8))) unsigned short ushort8v;
typedef __attribute__((ext_vector_type(8))) __bf16 bf16x8;
typedef __attribute__((ext_vector_type(4))) float floatx4;

__device__ __forceinline__ unsigned short f2b(float f) {
    unsigned u = __float_as_uint(f);
    unsigned r = u + 0x7fffu + ((u >> 16) & 1u);   // RNE
    return (unsigned short)(r >> 16);
}
__device__ __forceinline__ float b2f(unsigned short h) {
    return __uint_as_float(((unsigned)h) << 16);
}

// global -> LDS direct (16B/lane). Dest must be wave-uniform base + lane*16.
__device__ __forceinline__ void gload16(const unsigned short* g, unsigned short* l) {
    __builtin_amdgcn_global_load_lds(
        (const __attribute__((address_space(1))) unsigned int*)g,
        (__attribute__((address_space(3))) unsigned int*)l,
        16, 0, 0);
}

// ============================================================================
// Fragment-swizzled layout: tensor [T16][KC][16][8] bf16;
//   elem (t16, kc, l, e) = Mat[t16*16 + l][kc*8 + e]
// R10: all top-5 dispatches were gemm1 (WRITE=16.4MB=dec). 46.7us = 736 TF;
// per-step wall 3500cyc vs ~310cyc MFMA demand -> ~70% is the per-step
// __syncthreads vmcnt(0) drain exposing loaded-HBM latency (T4 lesson, m218).
// Rebuilt: 256x128 tile, 8 waves (4Mx2N, 64x64/wave), BK=32, 5-buffer
// counted-vmcnt pipeline (stage-ahead 4, vmcnt(12) steady, never 0 in main
// loop), raw s_barrier pairs, setprio around MFMA cluster. Grid 256 = 1/CU.
// LDS 5 x (A 16KB + B 8KB) = 120KB. K-accumulation order bitwise-identical.
// ============================================================================

// ---------- fused prep ----------
// blocks [0,2048):      x (8192x2048 f32) -> A2x swizzled bf16 (KC=256)
// blocks [2048,4096):   W (2048x1023 f32) -> B2w swizzled bf16 (KC=256)
// blocks [4096,5120):   softmax(leaf_dist) -> B2p swizzled bf16 (KC=128), c>=1000 zero
__global__ __launch_bounds__(256) void prep_kernel(const float* __restrict__ x,
                                                   unsigned short* __restrict__ A2x,
                                                   const float* __restrict__ W,
                                                   unsigned short* __restrict__ B2w,
                                                   const float* __restrict__ ld_,
                                                   unsigned short* __restrict__ B2p) {
    __shared__ float tile[32 * 33];
    __shared__ float buf[1000];
    __shared__ float red[8];
    const int b = blockIdx.x, t = threadIdx.x;
    if (b < 2048) {                        // ---- cvt+swizzle x: quarter of a 16-row slab ----
        const int mt = b >> 2, kq = (b & 3) * 64;
        const int kco = t >> 4, l16 = t & 15;       // kco 0..15
        const float* xr0 = x + (size_t)(mt * 16 + l16) * 2048;
#pragma unroll
        for (int i = 0; i < 4; i++) {
            const int kc = kq + i * 16 + kco;
            const float* xr = xr0 + kc * 8;
            float4 v0 = *(const float4*)xr;
            float4 v1 = *(const float4*)(xr + 4);
            ushort8v o;
            o[0] = f2b(v0.x); o[1] = f2b(v0.y); o[2] = f2b(v0.z); o[3] = f2b(v0.w);
            o[4] = f2b(v1.x); o[5] = f2b(v1.y); o[6] = f2b(v1.z); o[7] = f2b(v1.w);
            *(ushort8v*)(A2x + ((size_t)(mt * 256 + kc) * 16 + l16) * 8) = o;
        }
    } else if (b < 4096) {                 // ---- transpose+swizzle W ----
        const int idx = b - 2048;
        const int n0 = (idx & 31) * 32, k0 = (idx >> 5) * 32;
        const int tx = t & 31, ty = t >> 5;
#pragma unroll
        for (int i = 0; i < 4; i++) {
            int k = k0 + ty + i * 8, n = n0 + tx;
            tile[(ty + i * 8) * 33 + tx] = (n < 1023) ? W[(size_t)k * 1023 + n] : 0.f;
        }
        __syncthreads();
#pragma unroll
        for (int i = 0; i < 4; i++) {
            int n = n0 + ty + i * 8, k = k0 + tx;
            size_t off = ((size_t)((n >> 4) * 256 + (k >> 3)) * 16 + (n & 15)) * 8 + (k & 7);
            B2w[off] = f2b(tile[tx * 33 + ty + i * 8]);
        }
    } else {                               // ---- softmax -> B2p swizzled (+zero pad) ----
        const int l0 = b - 4096;
        const float* r = ld_ + (size_t)l0 * 1000;
        float mx = -3.4e38f;
        for (int i = t; i < 1000; i += 256) { float v = r[i]; buf[i] = v; mx = fmaxf(mx, v); }
#pragma unroll
        for (int o = 32; o > 0; o >>= 1) mx = fmaxf(mx, __shfl_down(mx, o));
        if ((t & 63) == 0) red[t >> 6] = mx;
        __syncthreads();
        mx = fmaxf(fmaxf(red[0], red[1]), fmaxf(red[2], red[3]));
        float s = 0.f;
        for (int i = t; i < 1000; i += 256) { float e = __expf(buf[i] - mx); buf[i] = e; s += e; }
#pragma unroll
        for (int o = 32; o > 0; o >>= 1) s += __shfl_down(s, o);
        if ((t & 63) == 0) red[4 + (t >> 6)] = s;
        __syncthreads();
        float inv = 1.f / (red[4] + red[5] + red[6] + red[7]);
        for (int i = t; i < 1024; i += 256) {
            float pv = (i < 1000) ? buf[i] * inv : 0.f;
            size_t off = ((size_t)((i >> 4) * 128 + (l0 >> 3)) * 16 + (i & 15)) * 8 + (l0 & 7);
            B2p[off] = f2b(pv);
        }
    }
}

// ---------- pp: 8 rows per block (barriers amortized), writes A2p swizzled ----------
// LDS: d 8x1024 bf16 (16KB) + pa/pb 8x1024 f32 (64KB) = 80KB -> 2 blocks/CU.
__global__ __launch_bounds__(256) void pp_kernel(const unsigned short* __restrict__ dec,
                                                 unsigned short* __restrict__ A2p) {
    __shared__ unsigned short dsh[8 * 1024];
    __shared__ float pa[8 * 1024];
    __shared__ float pb[8 * 1024];
    const int t = threadIdx.x;
    const int r0 = blockIdx.x * 8;
    // load 8 rows of dec (16KB contiguous) as ushort8
    {
        const ushort8v* src = (const ushort8v*)(dec + (size_t)r0 * 1024);
        ushort8v* dst = (ushort8v*)dsh;
        for (int g = t; g < 1024; g += 256) dst[g] = src[g];
    }
    if (t < 8) pa[t * 1024] = 1.f;
    __syncthreads();
    float* cur = pa; float* nxt = pb;
    for (int dep = 0; dep < 10; dep++) {
        const int half = 1 << dep;
        const int len  = half << 1;
        const int total = len << 3;        // 8 rows
        for (int idx = t; idx < total; idx += 256) {
            const int r = idx >> (dep + 1);
            const int j = idx & (len - 1);
            int tt = j >> dep;
            int s  = j & (half - 1);
            int i2 = 2 * s + tt;
            int u  = i2 >> dep;
            int rr = i2 & (half - 1);
            float dv = b2f(dsh[r * 1024 + half - 1 + rr]);
            nxt[r * 1024 + j] = cur[r * 1024 + rr] * (u ? (1.f - dv) : dv);
        }
        __syncthreads();
        float* tmp = cur; cur = nxt; nxt = tmp;
    }
    // write swizzled A2p (KC=128): off(row, j)
    for (int i = t; i < 8192; i += 256) {
        const int r = i >> 10, j = i & 1023;
        const int rrow = r0 + r;
        size_t off = ((size_t)((rrow >> 4) * 128 + (j >> 3)) * 16 + (rrow & 15)) * 8 + (j & 7);
        A2p[off] = f2b(cur[r * 1024 + j]);
    }
}

// ---------- counted-vmcnt pipelined GEMM: 256x128 tile, 8 waves, 5 buffers ----------
// Per buffer: A = 16 slabs x 4 kc-chunks = 64 chunks (16KB) at [0..8192),
//             B =  8 slabs x 4 kc-chunks = 32 chunks (8KB)  at [8192..12288).
// Stage per wave: A chunks [w*8,w*8+8) = 2 instrs, B chunks [w*4,w*4+4) = 1 instr
//   -> 3 VMEM/thread/step; steady vmcnt(12) = 4 stages in flight.
// Step: vmcnt(N); s_barrier; ds_read 8 frags; lgkmcnt(0); s_barrier;
//       stage ks+5 into the buffer just read; setprio(1); 16 MFMA; setprio(0).
// Tail: 5 peeled steps, vmcnt 12/9/6/3/0. No vmcnt(0) in main loop (T4).
#define VMW(N) asm volatile("s_waitcnt vmcnt(" #N ")" ::: "memory")

#define P5_STEP(ks_, b_, VM_, DOSTAGE_)                                           \
    {                                                                             \
        VMW(VM_);                                                                 \
        __builtin_amdgcn_s_barrier();                                             \
        __builtin_amdgcn_sched_barrier(0);                                        \
        const unsigned short* lA = &lds[(b_)][0];                                 \
        const unsigned short* lB = &lds[(b_)][8192];                              \
        bf16x8 af[4], bv[4];                                                      \
        _Pragma("unroll")                                                         \
        for (int m2 = 0; m2 < 4; m2++)                                            \
            af[m2] = __builtin_bit_cast(bf16x8,                                   \
                *(const ushort8v*)&lA[(wr * 4 + m2) * 512 + quad * 128 + l16 * 8]); \
        _Pragma("unroll")                                                         \
        for (int n2 = 0; n2 < 4; n2++)                                            \
            bv[n2] = __builtin_bit_cast(bf16x8,                                   \
                *(const ushort8v*)&lB[(wc * 4 + n2) * 512 + quad * 128 + l16 * 8]); \
        asm volatile("s_waitcnt lgkmcnt(0)" ::: "memory");                        \
        __builtin_amdgcn_sched_barrier(0);                                        \
        __builtin_amdgcn_s_barrier();                                             \
        __builtin_amdgcn_sched_barrier(0);                                        \
        if (DOSTAGE_) STAGE((ks_) + 5, (b_));                                     \
        __builtin_amdgcn_s_setprio(1);                                            \
        _Pragma("unroll")                                                         \
        for (int m2 = 0; m2 < 4; m2++)                                            \
            _Pragma("unroll")                                                     \
            for (int n2 = 0; n2 < 4; n2++)                                        \
                acc[m2][n2] = __builtin_amdgcn_mfma_f32_16x16x32_bf16(            \
                    af[m2], bv[n2], acc[m2][n2], 0, 0, 0);                        \
        __builtin_amdgcn_s_setprio(0);                                            \
    }

template <int EPI, int KC>
__global__ __launch_bounds__(512, 2) void gemm_p5(const unsigned short* __restrict__ A2,
                                                  const unsigned short* __restrict__ B2,
                                                  const float* __restrict__ bias,
                                                  unsigned short* __restrict__ obf,
                                                  float* __restrict__ of32, int ldo) {
    __shared__ unsigned short lds[5][12288];   // 5 bufs x 24KB = 120KB

    const int tid  = threadIdx.x;
    const int lane = tid & 63;
    const int wave = tid >> 6;                 // 0..7
    const int quad = lane >> 4, l16 = lane & 15;
    const int wr = wave >> 1, wc = wave & 1;   // 4M x 2N wave grid, 64x64/wave

    const int bid = blockIdx.x;
    const int xcd = bid & 7;
    const int j   = bid >> 3;                  // 0..31
    const int bm  = xcd * 4 + (j & 3);         // 256-row tile idx 0..31
    const int bn  = j >> 2;                    // 128-col tile idx 0..7

    // stage sources: A chunks c0=w*8+quad (slab w*2), c1=c0+4 (slab w*2+1);
    //                B chunk  cB=w*4+quad (slab w). All per-instr 1KB contiguous.
    const unsigned short* gA0 = A2 + ((size_t)(bm * 16 + wave * 2)     * KC + quad) * 128 + l16 * 8;
    const unsigned short* gA1 = A2 + ((size_t)(bm * 16 + wave * 2 + 1) * KC + quad) * 128 + l16 * 8;
    const unsigned short* gB0 = B2 + ((size_t)(bn * 8  + wave)         * KC + quad) * 128 + l16 * 8;
    const int dA0 = (wave * 8 + quad) * 128 + l16 * 8;        // = wave*1024 + lane*8
    const int dA1 = dA0 + 512;
    const int dB0 = 8192 + (wave * 4 + quad) * 128 + l16 * 8; // = 8192 + wave*512 + lane*8

    floatx4 acc[4][4] = {};
    constexpr int nks = KC / 4;                // BK=32 -> 4 kc-chunks/step

    auto STAGE = [&](int ks, int b) {
        const size_t ko = (size_t)ks * 512;    // 4 chunks * 128 ushorts
        gload16(gA0 + ko, &lds[b][dA0]);
        gload16(gA1 + ko, &lds[b][dA1]);
        gload16(gB0 + ko, &lds[b][dB0]);
    };

    // prologue: fill all 5 buffers
    STAGE(0, 0); STAGE(1, 1); STAGE(2, 2); STAGE(3, 3); STAGE(4, 4);

    int bb = 0;
    for (int ks = 0; ks < nks - 5; ++ks) {
        P5_STEP(ks, bb, 12, true);
        bb = (bb == 4) ? 0 : bb + 1;
    }
    P5_STEP(nks - 5, (nks - 5) % 5, 12, false);
    P5_STEP(nks - 4, (nks - 4) % 5, 9,  false);
    P5_STEP(nks - 3, (nks - 3) % 5, 6,  false);
    P5_STEP(nks - 2, (nks - 2) % 5, 3,  false);
    P5_STEP(nks - 1, (nks - 1) % 5, 0,  false);

    // ---- epilogue ----
    const int mt0 = bm * 16 + wr * 4;
    const int nt0 = bn * 8  + wc * 4;
#pragma unroll
    for (int n2 = 0; n2 < 4; n2++) {
        const int col = (nt0 + n2) * 16 + l16;
        float bbias = 0.f;
        if constexpr (EPI == 0) bbias = (col < 1023) ? bias[col] : 0.f;
#pragma unroll
        for (int m2 = 0; m2 < 4; m2++) {
            const int row0 = (mt0 + m2) * 16 + quad * 4;
#pragma unroll
            for (int r = 0; r < 4; r++) {
                float v = acc[m2][n2][r];
                if constexpr (EPI == 0) {
                    float sgm = 1.f / (1.f + __expf(-(v + bbias)));
                    obf[(size_t)(row0 + r) * ldo + col] = f2b(sgm);
                } else {
                    if (col < 1000) of32[(size_t)(row0 + r) * ldo + col] = v;
                }
            }
        }
    }
}

// ---------- host ----------
extern "C" void kernel_launch(void* const* d_in, const int* in_sizes, int n_in,
                              void* d_out, int out_size, void* d_ws, size_t ws_size,
                              hipStream_t stream) {
    const float* x   = (const float*)d_in[0];   // 8192x2048
    const float* W   = (const float*)d_in[1];   // 2048x1023
    const float* b   = (const float*)d_in[2];   // 1023
    const float* ldd = (const float*)d_in[3];   // 1024x1000
    float* out = (float*)d_out;                 // 8192x1000

    char* ws = (char*)d_ws;
    unsigned short* A2x = (unsigned short*)(ws);              // 33,554,432 B (swizzled x bf16)
    unsigned short* A2p = (unsigned short*)(ws);              // overlay: pp output (A2x dead by then)
    unsigned short* B2w = (unsigned short*)(ws + 33554432);   // 4,194,304 B (swizzled W^T)
    unsigned short* dec = (unsigned short*)(ws + 37748736);   // 16,777,216 B (row-major decisions)
    unsigned short* B2p = (unsigned short*)(ws + 54525952);   // 2,097,152 B (swizzled P^T)

    // prep: x-swizzle | W-transpose-swizzle | softmax->swizzle (independent)
    prep_kernel<<<5120, 256, 0, stream>>>(x, A2x, W, B2w, ldd, B2p);
    // decisions = sigmoid(x@W + b), row-major bf16 (cols padded to 1024)
    gemm_p5<0, 256><<<256, 512, 0, stream>>>(A2x, B2w, b, dec, nullptr, 1024);
    // pp (reference-literal order), 8 rows/block, writes swizzled A2p
    pp_kernel<<<1024, 256, 0, stream>>>(dec, A2p);
    // out = pp @ P
    gemm_p5<1, 128><<<256, 512, 0, stream>>>(A2p, B2p, nullptr, nullptr, out, 1000);
}